// Round 5
// baseline (731.037 us; speedup 1.0000x reference)
//
#include <hip/hip_runtime.h>

#define N_NODES 100000
#define N_EDGES 1600000
#define D 64

#define BN 64                               // nodes per bucket
#define NBUCK ((N_NODES + BN - 1) / BN)     // 1563
#define CHW 256                             // binning chunks (round-2 best: clustered)
#define CH ((N_EDGES + CHW - 1) / CHW)      // 6250 edges per chunk
#define CITER 13                            // ceil(CH/512)
#define CAP 2048                            // fixed bucket capacity in coarse
#define PAD 16                              // cursor padding (64 B) -> per-line atomics
#define OVFMAX 32768                        // global overflow list (never used in practice)
#define GEMM_THREADS (N_NODES * 16 / 2)     // 800000: 16 threads per row-pair
#define GEMM_BLKS ((GEMM_THREADS + 511) / 512)  // 1563
#define NBLK (CHW + GEMM_BLKS)              // 1819
#define STR 68                              // acc row stride (floats): 64 + 4 pad

static __device__ __forceinline__ unsigned short f2bf(float f) {
    unsigned u = __float_as_uint(f);
    u += 0x7FFFu + ((u >> 16) & 1u);
    return (unsigned short)(u >> 16);
}
static __device__ __forceinline__ float bf2f(unsigned short h) {
    return __uint_as_float((unsigned)h << 16);
}

// ---------------- fused main: blocks [0,CHW) bin edges, blocks [CHW,..) do GEMM ----
// EXACT round-2 structure (best measured: 60 us): clustered binning blocks,
// one-pass register staging (compiler may spill a few — measured faster than
// the two-pass or CHW=512 variants), nt loads, per-block run reservation.
__global__ __launch_bounds__(512) void gcn_main(const float* __restrict__ x,
                                                const float* __restrict__ w,
                                                unsigned short* __restrict__ support,
                                                const int* __restrict__ src,
                                                const int* __restrict__ dst,
                                                const float* __restrict__ adj,
                                                int* __restrict__ gcur,
                                                int* __restrict__ ovfcnt,
                                                int4* __restrict__ ovflist,
                                                int2* __restrict__ coarse) {
    __shared__ __align__(16) char smem[16384];
    int tid = threadIdx.x;
    int bid = blockIdx.x;

    if (bid < CHW) {
        // ---- binning role (register-staged chunk, per-block run reservation) ----
        int* h = (int*)smem;            // NBUCK counts
        int* cur = h + NBUCK;           // NBUCK cursors
        for (int i = tid; i < NBUCK; i += 512) h[i] = 0;
        __syncthreads();

        int e0 = bid * CH, e1 = min(e0 + CH, N_EDGES);
        int dreg[CITER], sreg[CITER];
        float areg[CITER];
        #pragma unroll
        for (int it = 0; it < CITER; ++it) {
            int e = e0 + tid + it * 512;
            dreg[it] = -1;
            if (e < e1) {
                dreg[it] = __builtin_nontemporal_load(&dst[e]);
                sreg[it] = __builtin_nontemporal_load(&src[e]);
                areg[it] = __builtin_nontemporal_load(&adj[e]);
                atomicAdd(&h[dreg[it] >> 6], 1);
            }
        }
        __syncthreads();

        for (int c = tid; c < NBUCK; c += 512) {
            int hc = h[c];
            if (hc) cur[c] = atomicAdd(&gcur[c * PAD], hc);
        }
        __syncthreads();

        #pragma unroll
        for (int it = 0; it < CITER; ++it) {
            if (dreg[it] >= 0) {
                int c = dreg[it] >> 6;
                int pos = atomicAdd(&cur[c], 1);
                if (pos < CAP) {
                    coarse[c * CAP + pos] =
                        make_int2(sreg[it] | ((dreg[it] & 63) << 17),
                                  __float_as_int(areg[it]));
                } else {
                    int op = atomicAdd(ovfcnt, 1);
                    if (op < OVFMAX)
                        ovflist[op] = make_int4(sreg[it], dreg[it],
                                                __float_as_int(areg[it]), 0);
                }
            }
        }
    } else {
        // ---- GEMM role: support(bf16) = X @ W ----
        float4* wsh = (float4*)smem;    // 64x16 float4 = 16 KB
        const float4* w4 = (const float4*)w;
        for (int i = tid; i < 64 * 16; i += 512) wsh[i] = w4[i];
        __syncthreads();

        int idx = (bid - CHW) * 512 + tid;
        if (idx < GEMM_THREADS) {
            int rowpair = idx >> 4;
            int c4 = idx & 15;
            long r0 = (long)rowpair * 2;
            const float4* xr0 = (const float4*)(x + r0 * D);
            const float4* xr1 = (const float4*)(x + (r0 + 1) * D);

            float4 a0 = make_float4(0.f, 0.f, 0.f, 0.f);
            float4 a1 = make_float4(0.f, 0.f, 0.f, 0.f);
            #pragma unroll 4
            for (int k4 = 0; k4 < 16; ++k4) {
                float4 xv0 = xr0[k4];
                float4 xv1 = xr1[k4];
                float4 w0 = wsh[(4 * k4 + 0) * 16 + c4];
                float4 w1 = wsh[(4 * k4 + 1) * 16 + c4];
                float4 w2 = wsh[(4 * k4 + 2) * 16 + c4];
                float4 w3 = wsh[(4 * k4 + 3) * 16 + c4];
                a0 += w0 * xv0.x + w1 * xv0.y + w2 * xv0.z + w3 * xv0.w;
                a1 += w0 * xv1.x + w1 * xv1.y + w2 * xv1.z + w3 * xv1.w;
            }
            ushort4* s4 = (ushort4*)support;
            s4[r0 * 16 + c4] = make_ushort4(f2bf(a0.x), f2bf(a0.y), f2bf(a0.z), f2bf(a0.w));
            s4[(r0 + 1) * 16 + c4] = make_ushort4(f2bf(a1.x), f2bf(a1.y), f2bf(a1.z), f2bf(a1.w));
        }
    }
}

// ---------------- gather v2: no sort — arrival-order edges into LDS f32 accs ------
// Each 16-lane group owns one edge per iteration: broadcast int2, 128B support
// row across 16 lanes, ds_add_f32 (no-return) into acc[nl][.]. Edges independent
// -> deep load ILP; sort/scan/recount all gone.
__global__ __launch_bounds__(256) void gcn_bgather(const unsigned short* __restrict__ support,
                                                   const int2* __restrict__ coarse,
                                                   const int* __restrict__ gcur,
                                                   const int* __restrict__ ovfcnt,
                                                   const int4* __restrict__ ovflist,
                                                   const float* __restrict__ bias,
                                                   float* __restrict__ out) {
    __shared__ float accS[BN * STR];        // 64 x 68 f32 = 17.4 KB (pad kills 8-way)

    int tid = threadIdx.x;
    int b = blockIdx.x;
    int tot = min(gcur[b * PAD], CAP);      // bucket edge count (post-binning cursor)
    const int2* ce = coarse + (long)b * CAP;

    for (int i = tid; i < BN * STR; i += 256) accS[i] = 0.f;
    __syncthreads();

    int g = tid >> 4;        // edge group 0..15
    int L = tid & 15;        // feature quad 0..15
    const uint2* sup2 = (const uint2*)support;     // 8 B = 4 bf16 features

    #pragma unroll 4
    for (int e = g; e < tot; e += 16) {
        int2 ed = ce[e];                    // 16 lanes same addr (broadcast)
        int nl = (ed.x >> 17) & 63;
        float wgt = __int_as_float(ed.y);
        uint2 p = sup2[(long)(ed.x & 0x1FFFF) * 16 + L];
        float* a = &accS[nl * STR + L * 4];
        atomicAdd(&a[0], wgt * __uint_as_float(p.x << 16));
        atomicAdd(&a[1], wgt * __uint_as_float(p.x & 0xFFFF0000u));
        atomicAdd(&a[2], wgt * __uint_as_float(p.y << 16));
        atomicAdd(&a[3], wgt * __uint_as_float(p.y & 0xFFFF0000u));
    }
    __syncthreads();

    // epilogue: acc + bias -> out (coalesced float4)
    const float4* bias4 = (const float4*)bias;
    float4* out4 = (float4*)out;
    for (int i = tid; i < BN * 16; i += 256) {
        int nl = i >> 4, q = i & 15;
        int n = b * BN + nl;
        if (n < N_NODES) {
            float4 bv = bias4[q];
            const float* a = &accS[nl * STR + q * 4];
            out4[(long)n * 16 + q] = make_float4(a[0] + bv.x, a[1] + bv.y,
                                                 a[2] + bv.z, a[3] + bv.w);
        }
    }

    // overflow tail (correctness only; ovfcnt == 0 for this input -> one load)
    __syncthreads();
    int lane = tid & 63, wv = tid >> 6;
    int no = min(*ovfcnt, OVFMAX);
    for (int i = wv; i < no; i += 4) {
        int4 ed = ovflist[i];
        if ((ed.y >> 6) == b) {
            float v = __int_as_float(ed.z) * bf2f(support[(long)ed.x * D + lane]);
            atomicAdd(&out[(long)ed.y * D + lane], v);
        }
    }
}

extern "C" void kernel_launch(void* const* d_in, const int* in_sizes, int n_in,
                              void* d_out, int out_size, void* d_ws, size_t ws_size,
                              hipStream_t stream) {
    const float* x      = (const float*)d_in[0];
    const float* weight = (const float*)d_in[1];
    const float* bias   = (const float*)d_in[2];
    const float* adj    = (const float*)d_in[3];
    const int*   src    = (const int*)d_in[4];
    const int*   dst    = (const int*)d_in[5];
    float* out = (float*)d_out;

    unsigned short* support = (unsigned short*)d_ws;          // 12,800,000 B
    int2* coarse = (int2*)(support + (long)N_NODES * D);      // NBUCK*CAP*8 = 25,608,192 B
    int*  gcur   = (int*)(coarse + (long)NBUCK * CAP);        // NBUCK*PAD*4 = 100,032 B
    int*  ovfcnt = gcur + NBUCK * PAD;                        // 16 B reserved
    int4* ovflist = (int4*)(ovfcnt + 4);                      // 524,288 B

    hipMemsetAsync(gcur, 0, NBUCK * PAD * sizeof(int) + 16, stream);
    hipLaunchKernelGGL(gcn_main, dim3(NBLK), dim3(512), 0, stream,
                       x, weight, support, src, dst, adj, gcur, ovfcnt, ovflist, coarse);
    hipLaunchKernelGGL(gcn_bgather, dim3(NBUCK), dim3(256), 0, stream,
                       support, coarse, gcur, ovfcnt, ovflist, bias, out);
}

// Round 6
// 195.377 us; speedup vs baseline: 3.7417x; 3.7417x over previous
//
#include <hip/hip_runtime.h>

#define N_NODES 100000
#define N_EDGES 1600000
#define D 64

#define BN 64                               // nodes per bucket
#define NBUCK ((N_NODES + BN - 1) / BN)     // 1563
#define CHW 256                             // binning chunks (round-2 best: clustered)
#define CH ((N_EDGES + CHW - 1) / CHW)      // 6250 edges per chunk
#define CITER 13                            // ceil(CH/512)
#define CAP 2048                            // fixed bucket capacity in coarse
#define SMAX 2048                           // LDS edge capacity (== CAP)
#define PAD 16                              // cursor padding (64 B) -> per-line atomics
#define OVFMAX 32768                        // global overflow list (never used in practice)
#define GEMM_THREADS (N_NODES * 16 / 2)     // 800000: 16 threads per row-pair
#define GEMM_BLKS ((GEMM_THREADS + 511) / 512)  // 1563
#define NBLK (CHW + GEMM_BLKS)              // 1819
#define GITER 8                             // ceil(CAP/256) staged edges per thread

static __device__ __forceinline__ unsigned short f2bf(float f) {
    unsigned u = __float_as_uint(f);
    u += 0x7FFFu + ((u >> 16) & 1u);
    return (unsigned short)(u >> 16);
}
static __device__ __forceinline__ float bf2f(unsigned short h) {
    return __uint_as_float((unsigned)h << 16);
}

// ---------------- fused main: blocks [0,CHW) bin edges, blocks [CHW,..) do GEMM ----
// EXACT round-2 structure (best measured: 60 us). Do not touch.
__global__ __launch_bounds__(512) void gcn_main(const float* __restrict__ x,
                                                const float* __restrict__ w,
                                                unsigned short* __restrict__ support,
                                                const int* __restrict__ src,
                                                const int* __restrict__ dst,
                                                const float* __restrict__ adj,
                                                int* __restrict__ gcur,
                                                int* __restrict__ ovfcnt,
                                                int4* __restrict__ ovflist,
                                                int2* __restrict__ coarse) {
    __shared__ __align__(16) char smem[16384];
    int tid = threadIdx.x;
    int bid = blockIdx.x;

    if (bid < CHW) {
        // ---- binning role (register-staged chunk, per-block run reservation) ----
        int* h = (int*)smem;            // NBUCK counts
        int* cur = h + NBUCK;           // NBUCK cursors
        for (int i = tid; i < NBUCK; i += 512) h[i] = 0;
        __syncthreads();

        int e0 = bid * CH, e1 = min(e0 + CH, N_EDGES);
        int dreg[CITER], sreg[CITER];
        float areg[CITER];
        #pragma unroll
        for (int it = 0; it < CITER; ++it) {
            int e = e0 + tid + it * 512;
            dreg[it] = -1;
            if (e < e1) {
                dreg[it] = __builtin_nontemporal_load(&dst[e]);
                sreg[it] = __builtin_nontemporal_load(&src[e]);
                areg[it] = __builtin_nontemporal_load(&adj[e]);
                atomicAdd(&h[dreg[it] >> 6], 1);
            }
        }
        __syncthreads();

        for (int c = tid; c < NBUCK; c += 512) {
            int hc = h[c];
            if (hc) cur[c] = atomicAdd(&gcur[c * PAD], hc);
        }
        __syncthreads();

        #pragma unroll
        for (int it = 0; it < CITER; ++it) {
            if (dreg[it] >= 0) {
                int c = dreg[it] >> 6;
                int pos = atomicAdd(&cur[c], 1);
                if (pos < CAP) {
                    coarse[c * CAP + pos] =
                        make_int2(sreg[it] | ((dreg[it] & 63) << 17),
                                  __float_as_int(areg[it]));
                } else {
                    int op = atomicAdd(ovfcnt, 1);
                    if (op < OVFMAX)
                        ovflist[op] = make_int4(sreg[it], dreg[it],
                                                __float_as_int(areg[it]), 0);
                }
            }
        }
    } else {
        // ---- GEMM role: support(bf16) = X @ W ----
        float4* wsh = (float4*)smem;    // 64x16 float4 = 16 KB
        const float4* w4 = (const float4*)w;
        for (int i = tid; i < 64 * 16; i += 512) wsh[i] = w4[i];
        __syncthreads();

        int idx = (bid - CHW) * 512 + tid;
        if (idx < GEMM_THREADS) {
            int rowpair = idx >> 4;
            int c4 = idx & 15;
            long r0 = (long)rowpair * 2;
            const float4* xr0 = (const float4*)(x + r0 * D);
            const float4* xr1 = (const float4*)(x + (r0 + 1) * D);

            float4 a0 = make_float4(0.f, 0.f, 0.f, 0.f);
            float4 a1 = make_float4(0.f, 0.f, 0.f, 0.f);
            #pragma unroll 4
            for (int k4 = 0; k4 < 16; ++k4) {
                float4 xv0 = xr0[k4];
                float4 xv1 = xr1[k4];
                float4 w0 = wsh[(4 * k4 + 0) * 16 + c4];
                float4 w1 = wsh[(4 * k4 + 1) * 16 + c4];
                float4 w2 = wsh[(4 * k4 + 2) * 16 + c4];
                float4 w3 = wsh[(4 * k4 + 3) * 16 + c4];
                a0 += w0 * xv0.x + w1 * xv0.y + w2 * xv0.z + w3 * xv0.w;
                a1 += w0 * xv1.x + w1 * xv1.y + w2 * xv1.z + w3 * xv1.w;
            }
            ushort4* s4 = (ushort4*)support;
            s4[r0 * 16 + c4] = make_ushort4(f2bf(a0.x), f2bf(a0.y), f2bf(a0.z), f2bf(a0.w));
            s4[(r0 + 1) * 16 + c4] = make_ushort4(f2bf(a1.x), f2bf(a1.y), f2bf(a1.z), f2bf(a1.w));
        }
    }
}

// ---------------- bgather: reg-staged counting sort + dual-node wide gather -------
__global__ __launch_bounds__(256) void gcn_bgather(const unsigned short* __restrict__ support,
                                                   const int2* __restrict__ coarse,
                                                   const int* __restrict__ gcur,
                                                   const int* __restrict__ ovfcnt,
                                                   const int4* __restrict__ ovflist,
                                                   const float* __restrict__ bias,
                                                   float* __restrict__ out) {
    __shared__ int2 sE[SMAX];       // 16 KB sorted edges
    __shared__ int cntS[BN], loffS[BN], curS[BN];

    int tid = threadIdx.x, wv = tid >> 6, lane = tid & 63;
    int b = blockIdx.x;
    int tot = min(gcur[b * PAD], CAP);      // bucket edge count (post-binning cursor)
    const int2* ce = coarse + (long)b * CAP;

    if (tid < BN) cntS[tid] = 0;
    __syncthreads();

    // stage this block's bucket edges in registers (single coarse read), count
    int2 ereg[GITER];
    #pragma unroll
    for (int k = 0; k < GITER; ++k) {
        int e = tid + k * 256;
        ereg[k].x = -1;
        if (e < tot) {
            ereg[k] = ce[e];
            atomicAdd(&cntS[(ereg[k].x >> 17) & 63], 1);
        }
    }
    __syncthreads();

    // wave-0 shfl inclusive scan of the 64 counters (2 barriers total)
    if (tid < 64) {
        int c = cntS[tid];
        int v = c;
        #pragma unroll
        for (int off = 1; off < 64; off <<= 1) {
            int t = __shfl_up(v, off, 64);
            if (lane >= off) v += t;
        }
        loffS[tid] = v - c;
        curS[tid]  = v - c;
    }
    __syncthreads();

    // place staged edges into LDS per-node-sorted (pos < tot <= SMAX always)
    #pragma unroll
    for (int k = 0; k < GITER; ++k) {
        if (ereg[k].x != -1) {
            int nl = (ereg[k].x >> 17) & 63;
            int pos = atomicAdd(&curS[nl], 1);
            sE[pos] = ereg[k];
        }
    }
    __syncthreads();

    // gather: wave wv owns nodes [wv*16, wv*16+16), processed as pairs (nl, nl+8)
    int eg = lane >> 4;      // edge sub-slot 0..3
    int L  = lane & 15;      // feature quad 0..15
    const uint2* sup2 = (const uint2*)support;     // 8 B = 4 bf16 features
    const float4* bias4 = (const float4*)bias;
    float4* out4 = (float4*)out;
    float4 bv = bias4[L];

    for (int pp = 0; pp < 8; ++pp) {
        int n0 = wv * 16 + pp;
        int n1 = wv * 16 + 8 + pp;
        int s0 = loffS[n0], a0v = cntS[n0];
        int s1 = loffS[n1], a1v = cntS[n1];
        float4 acc0 = make_float4(0.f, 0.f, 0.f, 0.f);
        float4 acc1 = make_float4(0.f, 0.f, 0.f, 0.f);
        int mx = max(a0v, a1v);
        for (int j = 0; j < mx; j += 16) {
            #pragma unroll
            for (int q = 0; q < 4; ++q) {
                int ei = j + q * 4 + eg;
                if (j < a0v) {
                    int2 ed = sE[s0 + min(ei, a0v - 1)];
                    float wgt = (ei < a0v) ? __int_as_float(ed.y) : 0.f;
                    uint2 p = sup2[(long)(ed.x & 0x1FFFF) * 16 + L];
                    acc0.x += wgt * __uint_as_float(p.x << 16);
                    acc0.y += wgt * __uint_as_float(p.x & 0xFFFF0000u);
                    acc0.z += wgt * __uint_as_float(p.y << 16);
                    acc0.w += wgt * __uint_as_float(p.y & 0xFFFF0000u);
                }
                if (j < a1v) {
                    int2 ed = sE[s1 + min(ei, a1v - 1)];
                    float wgt = (ei < a1v) ? __int_as_float(ed.y) : 0.f;
                    uint2 p = sup2[(long)(ed.x & 0x1FFFF) * 16 + L];
                    acc1.x += wgt * __uint_as_float(p.x << 16);
                    acc1.y += wgt * __uint_as_float(p.x & 0xFFFF0000u);
                    acc1.z += wgt * __uint_as_float(p.y << 16);
                    acc1.w += wgt * __uint_as_float(p.y & 0xFFFF0000u);
                }
            }
        }
        // reduce across the 4 edge-slot groups (two independent shfl chains)
        acc0.x += __shfl_xor(acc0.x, 16, 64); acc1.x += __shfl_xor(acc1.x, 16, 64);
        acc0.y += __shfl_xor(acc0.y, 16, 64); acc1.y += __shfl_xor(acc1.y, 16, 64);
        acc0.z += __shfl_xor(acc0.z, 16, 64); acc1.z += __shfl_xor(acc1.z, 16, 64);
        acc0.w += __shfl_xor(acc0.w, 16, 64); acc1.w += __shfl_xor(acc1.w, 16, 64);
        acc0.x += __shfl_xor(acc0.x, 32, 64); acc1.x += __shfl_xor(acc1.x, 32, 64);
        acc0.y += __shfl_xor(acc0.y, 32, 64); acc1.y += __shfl_xor(acc1.y, 32, 64);
        acc0.z += __shfl_xor(acc0.z, 32, 64); acc1.z += __shfl_xor(acc1.z, 32, 64);
        acc0.w += __shfl_xor(acc0.w, 32, 64); acc1.w += __shfl_xor(acc1.w, 32, 64);
        if (lane < 16) {
            int g0 = b * BN + n0;
            int g1 = b * BN + n1;
            if (g0 < N_NODES)
                out4[(long)g0 * 16 + L] = make_float4(acc0.x + bv.x, acc0.y + bv.y,
                                                      acc0.z + bv.z, acc0.w + bv.w);
            if (g1 < N_NODES)
                out4[(long)g1 * 16 + L] = make_float4(acc1.x + bv.x, acc1.y + bv.y,
                                                      acc1.z + bv.z, acc1.w + bv.w);
        }
    }

    // overflow tail (correctness only; ovfcnt == 0 for this input -> one load)
    __syncthreads();
    int no = min(*ovfcnt, OVFMAX);
    for (int i = wv; i < no; i += 4) {
        int4 ed = ovflist[i];
        if ((ed.y >> 6) == b) {
            float v = __int_as_float(ed.z) * bf2f(support[(long)ed.x * D + lane]);
            atomicAdd(&out[(long)ed.y * D + lane], v);
        }
    }
}

extern "C" void kernel_launch(void* const* d_in, const int* in_sizes, int n_in,
                              void* d_out, int out_size, void* d_ws, size_t ws_size,
                              hipStream_t stream) {
    const float* x      = (const float*)d_in[0];
    const float* weight = (const float*)d_in[1];
    const float* bias   = (const float*)d_in[2];
    const float* adj    = (const float*)d_in[3];
    const int*   src    = (const int*)d_in[4];
    const int*   dst    = (const int*)d_in[5];
    float* out = (float*)d_out;

    unsigned short* support = (unsigned short*)d_ws;          // 12,800,000 B
    int2* coarse = (int2*)(support + (long)N_NODES * D);      // NBUCK*CAP*8 = 25,608,192 B
    int*  gcur   = (int*)(coarse + (long)NBUCK * CAP);        // NBUCK*PAD*4 = 100,032 B
    int*  ovfcnt = gcur + NBUCK * PAD;                        // 16 B reserved
    int4* ovflist = (int4*)(ovfcnt + 4);                      // 524,288 B

    hipMemsetAsync(gcur, 0, NBUCK * PAD * sizeof(int) + 16, stream);
    hipLaunchKernelGGL(gcn_main, dim3(NBLK), dim3(512), 0, stream,
                       x, weight, support, src, dst, adj, gcur, ovfcnt, ovflist, coarse);
    hipLaunchKernelGGL(gcn_bgather, dim3(NBUCK), dim3(256), 0, stream,
                       support, coarse, gcur, ovfcnt, ovflist, bias, out);
}

// Round 7
// 183.021 us; speedup vs baseline: 3.9943x; 1.0675x over previous
//
#include <hip/hip_runtime.h>

#define N_NODES 100000
#define N_EDGES 1600000
#define D 64

#define BN 64                               // nodes per bucket
#define NBUCK ((N_NODES + BN - 1) / BN)     // 1563
#define CHW 256                             // binning chunks (clustered = best measured)
#define CH ((N_EDGES + CHW - 1) / CHW)      // 6250 edges per chunk
#define CITER 13                            // ceil(CH/512)
#define CAP 2048                            // fixed bucket capacity in coarse
#define SMAX 2048                           // LDS edge capacity (== CAP)
#define PAD 16                              // cursor padding (64 B) -> per-line atomics
#define OVFMAX 32768                        // global overflow list (never used in practice)
#define GEMM_THREADS (N_NODES * 16 / 2)     // 800000: 16 threads per row-pair
#define GEMM_BLKS ((GEMM_THREADS + 511) / 512)  // 1563
#define NBLK (CHW + GEMM_BLKS)              // 1819

static __device__ __forceinline__ unsigned short f2bf(float f) {
    unsigned u = __float_as_uint(f);
    u += 0x7FFFu + ((u >> 16) & 1u);
    return (unsigned short)(u >> 16);
}
static __device__ __forceinline__ float bf2f(unsigned short h) {
    return __uint_as_float((unsigned)h << 16);
}

// ---------------- fused main: blocks [0,CHW) bin edges, blocks [CHW,..) do GEMM ----
// Round-2 structure (best measured: main=60us). ONE change vs round-2: the gcur
// run-reservation loop iterates from a per-block rotated start, so the 256
// binning blocks don't sweep the 1563 cursor lines in lockstep (256-way ->
// ~1-2-way instantaneous contention on each padded line).
__global__ __launch_bounds__(512) void gcn_main(const float* __restrict__ x,
                                                const float* __restrict__ w,
                                                unsigned short* __restrict__ support,
                                                const int* __restrict__ src,
                                                const int* __restrict__ dst,
                                                const float* __restrict__ adj,
                                                int* __restrict__ gcur,
                                                int* __restrict__ ovfcnt,
                                                int4* __restrict__ ovflist,
                                                int2* __restrict__ coarse) {
    __shared__ __align__(16) char smem[16384];
    int tid = threadIdx.x;
    int bid = blockIdx.x;

    if (bid < CHW) {
        // ---- binning role (register-staged chunk, per-block run reservation) ----
        int* h = (int*)smem;            // NBUCK counts
        int* cur = h + NBUCK;           // NBUCK cursors
        for (int i = tid; i < NBUCK; i += 512) h[i] = 0;
        __syncthreads();

        int e0 = bid * CH, e1 = min(e0 + CH, N_EDGES);
        int dreg[CITER], sreg[CITER];
        float areg[CITER];
        #pragma unroll
        for (int it = 0; it < CITER; ++it) {
            int e = e0 + tid + it * 512;
            dreg[it] = -1;
            if (e < e1) {
                dreg[it] = __builtin_nontemporal_load(&dst[e]);
                sreg[it] = __builtin_nontemporal_load(&src[e]);
                areg[it] = __builtin_nontemporal_load(&adj[e]);
                atomicAdd(&h[dreg[it] >> 6], 1);
            }
        }
        __syncthreads();

        // staggered reservation: rotate this block's sweep start by bid*6 lines
        int rot = (bid * 6) % NBUCK;
        for (int i = tid; i < NBUCK; i += 512) {
            int c = i + rot;
            if (c >= NBUCK) c -= NBUCK;
            int hc = h[c];
            if (hc) cur[c] = atomicAdd(&gcur[c * PAD], hc);
        }
        __syncthreads();

        #pragma unroll
        for (int it = 0; it < CITER; ++it) {
            if (dreg[it] >= 0) {
                int c = dreg[it] >> 6;
                int pos = atomicAdd(&cur[c], 1);
                if (pos < CAP) {
                    coarse[c * CAP + pos] =
                        make_int2(sreg[it] | ((dreg[it] & 63) << 17),
                                  __float_as_int(areg[it]));
                } else {
                    int op = atomicAdd(ovfcnt, 1);
                    if (op < OVFMAX)
                        ovflist[op] = make_int4(sreg[it], dreg[it],
                                                __float_as_int(areg[it]), 0);
                }
            }
        }
    } else {
        // ---- GEMM role: support(bf16) = X @ W ----
        float4* wsh = (float4*)smem;    // 64x16 float4 = 16 KB
        const float4* w4 = (const float4*)w;
        for (int i = tid; i < 64 * 16; i += 512) wsh[i] = w4[i];
        __syncthreads();

        int idx = (bid - CHW) * 512 + tid;
        if (idx < GEMM_THREADS) {
            int rowpair = idx >> 4;
            int c4 = idx & 15;
            long r0 = (long)rowpair * 2;
            const float4* xr0 = (const float4*)(x + r0 * D);
            const float4* xr1 = (const float4*)(x + (r0 + 1) * D);

            float4 a0 = make_float4(0.f, 0.f, 0.f, 0.f);
            float4 a1 = make_float4(0.f, 0.f, 0.f, 0.f);
            #pragma unroll 4
            for (int k4 = 0; k4 < 16; ++k4) {
                float4 xv0 = xr0[k4];
                float4 xv1 = xr1[k4];
                float4 w0 = wsh[(4 * k4 + 0) * 16 + c4];
                float4 w1 = wsh[(4 * k4 + 1) * 16 + c4];
                float4 w2 = wsh[(4 * k4 + 2) * 16 + c4];
                float4 w3 = wsh[(4 * k4 + 3) * 16 + c4];
                a0 += w0 * xv0.x + w1 * xv0.y + w2 * xv0.z + w3 * xv0.w;
                a1 += w0 * xv1.x + w1 * xv1.y + w2 * xv1.z + w3 * xv1.w;
            }
            ushort4* s4 = (ushort4*)support;
            s4[r0 * 16 + c4] = make_ushort4(f2bf(a0.x), f2bf(a0.y), f2bf(a0.z), f2bf(a0.w));
            s4[(r0 + 1) * 16 + c4] = make_ushort4(f2bf(a1.x), f2bf(a1.y), f2bf(a1.z), f2bf(a1.w));
        }
    }
}

// ---------------- fused: per-bucket LDS counting sort + wide gather + ovf tail ----
// EXACT round-2 bgather (best measured). Do not touch.
__global__ __launch_bounds__(256) void gcn_bgather(const unsigned short* __restrict__ support,
                                                   const int2* __restrict__ coarse,
                                                   const int* __restrict__ gcur,
                                                   const int* __restrict__ ovfcnt,
                                                   const int4* __restrict__ ovflist,
                                                   const float* __restrict__ bias,
                                                   float* __restrict__ out) {
    __shared__ int2 sE[SMAX];       // 16 KB sorted edges
    __shared__ int cntS[BN], loffS[BN], curS[BN];

    int tid = threadIdx.x, wv = tid >> 6, lane = tid & 63;
    int b = blockIdx.x;
    int tot = min(gcur[b * PAD], CAP);      // bucket edge count (post-binning cursor)
    const int2* ce = coarse + (long)b * CAP;

    if (tid < BN) cntS[tid] = 0;
    __syncthreads();

    // phase A: count per-node (bucket section is L2-warm)
    for (int e = tid; e < tot; e += 256)
        atomicAdd(&cntS[(ce[e].x >> 17) & 63], 1);
    __syncthreads();

    // scan 64 counters
    if (tid < BN) loffS[tid] = cntS[tid];
    __syncthreads();
    for (int off = 1; off < BN; off <<= 1) {
        int t = 0;
        if (tid < BN && tid >= off) t = loffS[tid - off];
        __syncthreads();
        if (tid < BN && tid >= off) loffS[tid] += t;
        __syncthreads();
    }
    if (tid < BN) {
        int excl = loffS[tid] - cntS[tid];
        loffS[tid] = excl;
        curS[tid] = excl;
    }
    __syncthreads();

    // phase B: place edges into LDS per-node-sorted (pos < tot <= SMAX always)
    for (int e = tid; e < tot; e += 256) {
        int2 ed = ce[e];
        int nl = (ed.x >> 17) & 63;
        int pos = atomicAdd(&curS[nl], 1);
        sE[pos] = ed;
    }
    __syncthreads();

    // gather: wave wv owns local nodes [wv*16, wv*16+16)
    int eg = lane >> 4;      // edge sub-slot 0..3
    int L  = lane & 15;      // feature quad 0..15
    const uint2* sup2 = (const uint2*)support;     // 8 B = 4 bf16 features
    const float4* bias4 = (const float4*)bias;
    float4* out4 = (float4*)out;
    float4 bv = bias4[L];

    for (int nl = wv * 16; nl < wv * 16 + 16; ++nl) {
        int start = loffS[nl];
        int avail = cntS[nl];
        float4 acc = make_float4(0.f, 0.f, 0.f, 0.f);
        #pragma unroll 2
        for (int j = 0; j < avail; j += 16) {
            #pragma unroll
            for (int q = 0; q < 4; ++q) {
                int ei = j + q * 4 + eg;
                int2 ed = sE[start + min(ei, avail - 1)];
                float wgt = (ei < avail) ? __int_as_float(ed.y) : 0.f;
                uint2 p = sup2[(long)(ed.x & 0x1FFFF) * 16 + L];
                acc.x += wgt * __uint_as_float(p.x << 16);
                acc.y += wgt * __uint_as_float(p.x & 0xFFFF0000u);
                acc.z += wgt * __uint_as_float(p.y << 16);
                acc.w += wgt * __uint_as_float(p.y & 0xFFFF0000u);
            }
        }
        // reduce across the 4 edge-slot groups
        acc.x += __shfl_xor(acc.x, 16, 64); acc.y += __shfl_xor(acc.y, 16, 64);
        acc.z += __shfl_xor(acc.z, 16, 64); acc.w += __shfl_xor(acc.w, 16, 64);
        acc.x += __shfl_xor(acc.x, 32, 64); acc.y += __shfl_xor(acc.y, 32, 64);
        acc.z += __shfl_xor(acc.z, 32, 64); acc.w += __shfl_xor(acc.w, 32, 64);
        int n = b * BN + nl;
        if (lane < 16 && n < N_NODES) {
            float4 r = make_float4(acc.x + bv.x, acc.y + bv.y,
                                   acc.z + bv.z, acc.w + bv.w);
            out4[(long)n * 16 + L] = r;
        }
    }

    // overflow tail (correctness only; ovfcnt == 0 for this input -> one load)
    __syncthreads();
    int no = min(*ovfcnt, OVFMAX);
    for (int i = wv; i < no; i += 4) {
        int4 ed = ovflist[i];
        if ((ed.y >> 6) == b) {
            float v = __int_as_float(ed.z) * bf2f(support[(long)ed.x * D + lane]);
            atomicAdd(&out[(long)ed.y * D + lane], v);
        }
    }
}

extern "C" void kernel_launch(void* const* d_in, const int* in_sizes, int n_in,
                              void* d_out, int out_size, void* d_ws, size_t ws_size,
                              hipStream_t stream) {
    const float* x      = (const float*)d_in[0];
    const float* weight = (const float*)d_in[1];
    const float* bias   = (const float*)d_in[2];
    const float* adj    = (const float*)d_in[3];
    const int*   src    = (const int*)d_in[4];
    const int*   dst    = (const int*)d_in[5];
    float* out = (float*)d_out;

    unsigned short* support = (unsigned short*)d_ws;          // 12,800,000 B
    int2* coarse = (int2*)(support + (long)N_NODES * D);      // NBUCK*CAP*8 = 25,608,192 B
    int*  gcur   = (int*)(coarse + (long)NBUCK * CAP);        // NBUCK*PAD*4 = 100,032 B
    int*  ovfcnt = gcur + NBUCK * PAD;                        // 16 B reserved
    int4* ovflist = (int4*)(ovfcnt + 4);                      // 524,288 B

    hipMemsetAsync(gcur, 0, NBUCK * PAD * sizeof(int) + 16, stream);
    hipLaunchKernelGGL(gcn_main, dim3(NBLK), dim3(512), 0, stream,
                       x, weight, support, src, dst, adj, gcur, ovfcnt, ovflist, coarse);
    hipLaunchKernelGGL(gcn_bgather, dim3(NBUCK), dim3(256), 0, stream,
                       support, coarse, gcur, ovfcnt, ovflist, bias, out);
}

// Round 8
// 172.319 us; speedup vs baseline: 4.2424x; 1.0621x over previous
//
#include <hip/hip_runtime.h>

#define N_NODES 100000
#define N_EDGES 1600000
#define D 64

#define BN 64                               // nodes per bucket
#define NBUCK ((N_NODES + BN - 1) / BN)     // 1563
#define CHW 256                             // binning chunks (clustered = best measured)
#define CH ((N_EDGES + CHW - 1) / CHW)      // 6250 edges per chunk
#define CITER 13                            // ceil(CH/512)
#define CAP 2048                            // fixed bucket capacity in coarse
#define SMAX 2048                           // LDS edge capacity (== CAP)
#define PAD 16                              // cursor padding (64 B) -> per-line atomics
#define OVFMAX 32768                        // global overflow list (never used in practice)
#define GEMM_THREADS (N_NODES * 16 / 2)     // 800000: 16 threads per row-pair
#define GEMM_BLKS ((GEMM_THREADS + 511) / 512)  // 1563
#define NBLK (CHW + GEMM_BLKS)              // 1819
#define GT 512                              // bgather threads (was 256): 8 waves/bucket

static __device__ __forceinline__ unsigned short f2bf(float f) {
    unsigned u = __float_as_uint(f);
    u += 0x7FFFu + ((u >> 16) & 1u);
    return (unsigned short)(u >> 16);
}
static __device__ __forceinline__ float bf2f(unsigned short h) {
    return __uint_as_float((unsigned)h << 16);
}

// ---------------- fused main: blocks [0,CHW) bin edges, blocks [CHW,..) do GEMM ----
// EXACT round-2 structure (best measured: main = 59.8-60.3 us over 3 runs). FROZEN.
__global__ __launch_bounds__(512) void gcn_main(const float* __restrict__ x,
                                                const float* __restrict__ w,
                                                unsigned short* __restrict__ support,
                                                const int* __restrict__ src,
                                                const int* __restrict__ dst,
                                                const float* __restrict__ adj,
                                                int* __restrict__ gcur,
                                                int* __restrict__ ovfcnt,
                                                int4* __restrict__ ovflist,
                                                int2* __restrict__ coarse) {
    __shared__ __align__(16) char smem[16384];
    int tid = threadIdx.x;
    int bid = blockIdx.x;

    if (bid < CHW) {
        // ---- binning role (register-staged chunk, per-block run reservation) ----
        int* h = (int*)smem;            // NBUCK counts
        int* cur = h + NBUCK;           // NBUCK cursors
        for (int i = tid; i < NBUCK; i += 512) h[i] = 0;
        __syncthreads();

        int e0 = bid * CH, e1 = min(e0 + CH, N_EDGES);
        int dreg[CITER], sreg[CITER];
        float areg[CITER];
        #pragma unroll
        for (int it = 0; it < CITER; ++it) {
            int e = e0 + tid + it * 512;
            dreg[it] = -1;
            if (e < e1) {
                dreg[it] = __builtin_nontemporal_load(&dst[e]);
                sreg[it] = __builtin_nontemporal_load(&src[e]);
                areg[it] = __builtin_nontemporal_load(&adj[e]);
                atomicAdd(&h[dreg[it] >> 6], 1);
            }
        }
        __syncthreads();

        for (int c = tid; c < NBUCK; c += 512) {
            int hc = h[c];
            if (hc) cur[c] = atomicAdd(&gcur[c * PAD], hc);
        }
        __syncthreads();

        #pragma unroll
        for (int it = 0; it < CITER; ++it) {
            if (dreg[it] >= 0) {
                int c = dreg[it] >> 6;
                int pos = atomicAdd(&cur[c], 1);
                if (pos < CAP) {
                    coarse[c * CAP + pos] =
                        make_int2(sreg[it] | ((dreg[it] & 63) << 17),
                                  __float_as_int(areg[it]));
                } else {
                    int op = atomicAdd(ovfcnt, 1);
                    if (op < OVFMAX)
                        ovflist[op] = make_int4(sreg[it], dreg[it],
                                                __float_as_int(areg[it]), 0);
                }
            }
        }
    } else {
        // ---- GEMM role: support(bf16) = X @ W ----
        float4* wsh = (float4*)smem;    // 64x16 float4 = 16 KB
        const float4* w4 = (const float4*)w;
        for (int i = tid; i < 64 * 16; i += 512) wsh[i] = w4[i];
        __syncthreads();

        int idx = (bid - CHW) * 512 + tid;
        if (idx < GEMM_THREADS) {
            int rowpair = idx >> 4;
            int c4 = idx & 15;
            long r0 = (long)rowpair * 2;
            const float4* xr0 = (const float4*)(x + r0 * D);
            const float4* xr1 = (const float4*)(x + (r0 + 1) * D);

            float4 a0 = make_float4(0.f, 0.f, 0.f, 0.f);
            float4 a1 = make_float4(0.f, 0.f, 0.f, 0.f);
            #pragma unroll 4
            for (int k4 = 0; k4 < 16; ++k4) {
                float4 xv0 = xr0[k4];
                float4 xv1 = xr1[k4];
                float4 w0 = wsh[(4 * k4 + 0) * 16 + c4];
                float4 w1 = wsh[(4 * k4 + 1) * 16 + c4];
                float4 w2 = wsh[(4 * k4 + 2) * 16 + c4];
                float4 w3 = wsh[(4 * k4 + 3) * 16 + c4];
                a0 += w0 * xv0.x + w1 * xv0.y + w2 * xv0.z + w3 * xv0.w;
                a1 += w0 * xv1.x + w1 * xv1.y + w2 * xv1.z + w3 * xv1.w;
            }
            ushort4* s4 = (ushort4*)support;
            s4[r0 * 16 + c4] = make_ushort4(f2bf(a0.x), f2bf(a0.y), f2bf(a0.z), f2bf(a0.w));
            s4[(r0 + 1) * 16 + c4] = make_ushort4(f2bf(a1.x), f2bf(a1.y), f2bf(a1.z), f2bf(a1.w));
        }
    }
}

// ---------------- bgather: round-2 structure, 512 threads (8 waves x 8 nodes) -----
// Identical phases and inner gather pattern to the round-2 best; only the thread
// count changed (256 -> 512): phases A/B take half the iterations, and each wave's
// serial node chain halves (8 nodes instead of 16).
__global__ __launch_bounds__(GT) void gcn_bgather(const unsigned short* __restrict__ support,
                                                  const int2* __restrict__ coarse,
                                                  const int* __restrict__ gcur,
                                                  const int* __restrict__ ovfcnt,
                                                  const int4* __restrict__ ovflist,
                                                  const float* __restrict__ bias,
                                                  float* __restrict__ out) {
    __shared__ int2 sE[SMAX];       // 16 KB sorted edges
    __shared__ int cntS[BN], loffS[BN], curS[BN];

    int tid = threadIdx.x, wv = tid >> 6, lane = tid & 63;
    int b = blockIdx.x;
    int tot = min(gcur[b * PAD], CAP);      // bucket edge count (post-binning cursor)
    const int2* ce = coarse + (long)b * CAP;

    if (tid < BN) cntS[tid] = 0;
    __syncthreads();

    // phase A: count per-node (bucket section is L2-warm)
    for (int e = tid; e < tot; e += GT)
        atomicAdd(&cntS[(ce[e].x >> 17) & 63], 1);
    __syncthreads();

    // scan 64 counters
    if (tid < BN) loffS[tid] = cntS[tid];
    __syncthreads();
    for (int off = 1; off < BN; off <<= 1) {
        int t = 0;
        if (tid < BN && tid >= off) t = loffS[tid - off];
        __syncthreads();
        if (tid < BN && tid >= off) loffS[tid] += t;
        __syncthreads();
    }
    if (tid < BN) {
        int excl = loffS[tid] - cntS[tid];
        loffS[tid] = excl;
        curS[tid] = excl;
    }
    __syncthreads();

    // phase B: place edges into LDS per-node-sorted (pos < tot <= SMAX always)
    for (int e = tid; e < tot; e += GT) {
        int2 ed = ce[e];
        int nl = (ed.x >> 17) & 63;
        int pos = atomicAdd(&curS[nl], 1);
        sE[pos] = ed;
    }
    __syncthreads();

    // gather: wave wv owns local nodes [wv*8, wv*8+8)
    int eg = lane >> 4;      // edge sub-slot 0..3
    int L  = lane & 15;      // feature quad 0..15
    const uint2* sup2 = (const uint2*)support;     // 8 B = 4 bf16 features
    const float4* bias4 = (const float4*)bias;
    float4* out4 = (float4*)out;
    float4 bv = bias4[L];

    for (int nl = wv * 8; nl < wv * 8 + 8; ++nl) {
        int start = loffS[nl];
        int avail = cntS[nl];
        float4 acc = make_float4(0.f, 0.f, 0.f, 0.f);
        #pragma unroll 2
        for (int j = 0; j < avail; j += 16) {
            #pragma unroll
            for (int q = 0; q < 4; ++q) {
                int ei = j + q * 4 + eg;
                int2 ed = sE[start + min(ei, avail - 1)];
                float wgt = (ei < avail) ? __int_as_float(ed.y) : 0.f;
                uint2 p = sup2[(long)(ed.x & 0x1FFFF) * 16 + L];
                acc.x += wgt * __uint_as_float(p.x << 16);
                acc.y += wgt * __uint_as_float(p.x & 0xFFFF0000u);
                acc.z += wgt * __uint_as_float(p.y << 16);
                acc.w += wgt * __uint_as_float(p.y & 0xFFFF0000u);
            }
        }
        // reduce across the 4 edge-slot groups
        acc.x += __shfl_xor(acc.x, 16, 64); acc.y += __shfl_xor(acc.y, 16, 64);
        acc.z += __shfl_xor(acc.z, 16, 64); acc.w += __shfl_xor(acc.w, 16, 64);
        acc.x += __shfl_xor(acc.x, 32, 64); acc.y += __shfl_xor(acc.y, 32, 64);
        acc.z += __shfl_xor(acc.z, 32, 64); acc.w += __shfl_xor(acc.w, 32, 64);
        int n = b * BN + nl;
        if (lane < 16 && n < N_NODES) {
            float4 r = make_float4(acc.x + bv.x, acc.y + bv.y,
                                   acc.z + bv.z, acc.w + bv.w);
            out4[(long)n * 16 + L] = r;
        }
    }

    // overflow tail (correctness only; ovfcnt == 0 for this input -> one load)
    __syncthreads();
    int no = min(*ovfcnt, OVFMAX);
    for (int i = wv; i < no; i += 8) {
        int4 ed = ovflist[i];
        if ((ed.y >> 6) == b) {
            float v = __int_as_float(ed.z) * bf2f(support[(long)ed.x * D + lane]);
            atomicAdd(&out[(long)ed.y * D + lane], v);
        }
    }
}

extern "C" void kernel_launch(void* const* d_in, const int* in_sizes, int n_in,
                              void* d_out, int out_size, void* d_ws, size_t ws_size,
                              hipStream_t stream) {
    const float* x      = (const float*)d_in[0];
    const float* weight = (const float*)d_in[1];
    const float* bias   = (const float*)d_in[2];
    const float* adj    = (const float*)d_in[3];
    const int*   src    = (const int*)d_in[4];
    const int*   dst    = (const int*)d_in[5];
    float* out = (float*)d_out;

    unsigned short* support = (unsigned short*)d_ws;          // 12,800,000 B
    int2* coarse = (int2*)(support + (long)N_NODES * D);      // NBUCK*CAP*8 = 25,608,192 B
    int*  gcur   = (int*)(coarse + (long)NBUCK * CAP);        // NBUCK*PAD*4 = 100,032 B
    int*  ovfcnt = gcur + NBUCK * PAD;                        // 16 B reserved
    int4* ovflist = (int4*)(ovfcnt + 4);                      // 524,288 B

    hipMemsetAsync(gcur, 0, NBUCK * PAD * sizeof(int) + 16, stream);
    hipLaunchKernelGGL(gcn_main, dim3(NBLK), dim3(512), 0, stream,
                       x, weight, support, src, dst, adj, gcur, ovfcnt, ovflist, coarse);
    hipLaunchKernelGGL(gcn_bgather, dim3(NBUCK), dim3(GT), 0, stream,
                       support, coarse, gcur, ovfcnt, ovflist, bias, out);
}